// Round 21
// baseline (252.102 us; speedup 1.0000x reference)
//
#include <hip/hip_runtime.h>

#define D 64
#define NREL 3
#define SRC_MASK 0x1FFFF      // 17 bits: N=100000 < 2^17
#define ATHR 512
#define APT 8
#define ABLK (ATHR * APT)     // 4096 edges per block (bhist, binA)
#define BSH 9                 // 512-node buckets
#define BSZ 512

typedef unsigned short bf16_t;
typedef __attribute__((ext_vector_type(8))) short short8v;   // 8 bf16 = 4 VGPRs
typedef __attribute__((ext_vector_type(4))) float float4v;

__device__ __forceinline__ float bf2f(unsigned int u16) {
  return __uint_as_float(u16 << 16);
}
__device__ __forceinline__ unsigned int f2bf(float f) {
  unsigned int x = __float_as_uint(f);
  return (x + 0x7fffu + ((x >> 16) & 1u)) >> 16;  // round-to-nearest-even
}

// ---------------- tiny zero ----------------
__global__ __launch_bounds__(512) void zero_kernel(int* __restrict__ a,
                                                   int* __restrict__ b, int n) {
  const int t = threadIdx.x;
  for (int i = t; i < n; i += 512) { a[i] = 0; b[i] = 0; }
}

// ---------------- f32 -> bf16 convert (layer-1 input) ----------------
__global__ __launch_bounds__(256) void conv_kernel(
    const float* __restrict__ in, bf16_t* __restrict__ out, int n4) {
  const int i = blockIdx.x * 256 + threadIdx.x;
  if (i >= n4) return;
  const float4 f = reinterpret_cast<const float4*>(in)[i];
  uint2 o;
  o.x = f2bf(f.x) | (f2bf(f.y) << 16);
  o.y = f2bf(f.z) | (f2bf(f.w) << 16);
  reinterpret_cast<uint2*>(out)[i] = o;
}

// ---------------- CSR build (bucket-level only) ----------------
__global__ __launch_bounds__(ATHR) void bhist_kernel(
    const int* __restrict__ dst, int* __restrict__ bdeg, int n_edges, int nb) {
  __shared__ int cnt[200];
  const int t = threadIdx.x;
  for (int b = t; b < nb; b += ATHR) cnt[b] = 0;
  __syncthreads();
  const long e0 = (long)blockIdx.x * ABLK;
#pragma unroll
  for (int i = 0; i < APT; ++i) {
    const long e = e0 + t + (long)i * ATHR;
    if (e < n_edges) atomicAdd(&cnt[dst[e] >> BSH], 1);
  }
  __syncthreads();
  for (int b = t; b < nb; b += ATHR)
    if (cnt[b]) atomicAdd(&bdeg[b], cnt[b]);
}

__global__ __launch_bounds__(512) void bscan_kernel(
    const int* __restrict__ bdeg, int* __restrict__ boffs, int nb) {
  __shared__ int s[512];
  const int t = threadIdx.x;
  const int v = (t < nb) ? bdeg[t] : 0;
  s[t] = v;
  __syncthreads();
  for (int off = 1; off < 512; off <<= 1) {
    const int add = (t >= off) ? s[t - off] : 0;
    __syncthreads();
    s[t] += add;
    __syncthreads();
  }
  if (t < nb) boffs[t] = s[t] - v;
  if (t == 511) boffs[nb] = s[nb - 1];
}

// Phase A (R19-verified staged-flush version).
__global__ __launch_bounds__(ATHR) void binA_kernel(
    const int* __restrict__ src, const int* __restrict__ dst,
    const int* __restrict__ rel, const float* __restrict__ norm,
    const int* __restrict__ boffs, int* __restrict__ bcur,
    int2* __restrict__ binpay, int n_edges, int nb) {
  __shared__ int cnt[256];
  __shared__ int incl[256];
  __shared__ int gbase[200];
  __shared__ int2 staged[ABLK];
  __shared__ unsigned char sbk[ABLK];
  const int t = threadIdx.x;
  const long e0 = (long)blockIdx.x * ABLK;

  for (int b = t; b < 256; b += ATHR) cnt[b] = 0;
  __syncthreads();

  int2 pay[APT];
  int bk[APT], slot[APT];
#pragma unroll
  for (int i = 0; i < APT; ++i) {
    const long e = e0 + t + (long)i * ATHR;
    if (e < n_edges) {
      const int d = dst[e];
      bk[i] = d >> BSH;
      pay[i] = make_int2(src[e] | (rel[e] << 17) | ((d & (BSZ - 1)) << 19),
                         __float_as_int(norm[e]));
      slot[i] = atomicAdd(&cnt[bk[i]], 1);
    } else {
      bk[i] = -1;
    }
  }
  __syncthreads();

  if (t < 256) incl[t] = cnt[t];
  __syncthreads();
  for (int off = 1; off < 256; off <<= 1) {
    int add = 0;
    if (t < 256 && t >= off) add = incl[t - off];
    __syncthreads();
    if (t < 256) incl[t] += add;
    __syncthreads();
  }

  for (int b = t; b < nb; b += ATHR) {
    const int c = cnt[b];
    gbase[b] = c ? (boffs[b] + atomicAdd(&bcur[b], c)) : 0;
  }
  __syncthreads();

#pragma unroll
  for (int i = 0; i < APT; ++i) {
    if (bk[i] >= 0) {
      const int pos = incl[bk[i]] - cnt[bk[i]] + slot[i];
      staged[pos] = pay[i];
      sbk[pos] = (unsigned char)bk[i];
    }
  }
  __syncthreads();

  const int nv = (int)min((long)ABLK, (long)(n_edges - e0));
  for (int j = t; j < nv; j += ATHR) {
    const int b = sbk[j];
    const int excl = incl[b] - cnt[b];
    binpay[gbase[b] + j - excl] = staged[j];
  }
}

// Phase B: one 512-thread block per 512-node bucket (R16-verified).
__global__ __launch_bounds__(512) void binB_kernel(
    const int2* __restrict__ binpay, const int* __restrict__ boffs,
    int2* __restrict__ edgebuf, int* __restrict__ deg, int* __restrict__ offs,
    int n_nodes) {
  __shared__ int cnt[512];
  __shared__ int ss[512];
  __shared__ int cur[512];
  const int b = blockIdx.x;
  const int t = threadIdx.x;
  cnt[t] = 0;
  __syncthreads();
  const int start = boffs[b];
  const int end = boffs[b + 1];
  for (int i = start + t; i < end; i += 512)
    atomicAdd(&cnt[((unsigned)binpay[i].x >> 19) & (BSZ - 1)], 1);
  __syncthreads();
  const int v = cnt[t];
  ss[t] = v;
  __syncthreads();
  for (int off = 1; off < 512; off <<= 1) {
    const int add = (t >= off) ? ss[t - off] : 0;
    __syncthreads();
    ss[t] += add;
    __syncthreads();
  }
  const int excl = ss[t] - v;
  cur[t] = excl;
  const int node = (b << BSH) + t;
  if (node < n_nodes) {
    deg[node] = v;
    offs[node] = start + excl;
  }
  __syncthreads();
  for (int i = start + t; i < end; i += 512) {
    const int2 pay = binpay[i];
    const int dl = ((unsigned)pay.x >> 19) & (BSZ - 1);
    const int pos = start + atomicAdd(&cur[dl], 1);
    edgebuf[pos] = pay;
  }
}

// ---------------- aggregate-first gather (R20-verified: xb set L3-resident) -----
#define ACC_EDGE(V, NF, RR)                                               \
  do {                                                                    \
    const unsigned ww0 = V.x, ww1 = V.y, ww2 = V.z, ww3 = V.w;            \
    const float nf_ = NF;                                                 \
    if (RR == 0) {                                                        \
      a0[0] += bf2f(ww0 & 0xffff) * nf_; a0[1] += bf2f(ww0 >> 16) * nf_;  \
      a0[2] += bf2f(ww1 & 0xffff) * nf_; a0[3] += bf2f(ww1 >> 16) * nf_;  \
      a0[4] += bf2f(ww2 & 0xffff) * nf_; a0[5] += bf2f(ww2 >> 16) * nf_;  \
      a0[6] += bf2f(ww3 & 0xffff) * nf_; a0[7] += bf2f(ww3 >> 16) * nf_;  \
    } else if (RR == 1) {                                                 \
      a1[0] += bf2f(ww0 & 0xffff) * nf_; a1[1] += bf2f(ww0 >> 16) * nf_;  \
      a1[2] += bf2f(ww1 & 0xffff) * nf_; a1[3] += bf2f(ww1 >> 16) * nf_;  \
      a1[4] += bf2f(ww2 & 0xffff) * nf_; a1[5] += bf2f(ww2 >> 16) * nf_;  \
      a1[6] += bf2f(ww3 & 0xffff) * nf_; a1[7] += bf2f(ww3 >> 16) * nf_;  \
    } else {                                                              \
      a2[0] += bf2f(ww0 & 0xffff) * nf_; a2[1] += bf2f(ww0 >> 16) * nf_;  \
      a2[2] += bf2f(ww1 & 0xffff) * nf_; a2[3] += bf2f(ww1 >> 16) * nf_;  \
      a2[4] += bf2f(ww2 & 0xffff) * nf_; a2[5] += bf2f(ww2 >> 16) * nf_;  \
      a2[6] += bf2f(ww3 & 0xffff) * nf_; a2[7] += bf2f(ww3 >> 16) * nf_;  \
    }                                                                     \
  } while (0)

__global__ __launch_bounds__(256) void gather_agg_kernel(
    const bf16_t* __restrict__ xb, const int2* __restrict__ edgebuf,
    const int* __restrict__ offs, const int* __restrict__ deg,
    bf16_t* __restrict__ agg, int n_nodes) {
  const long gid = (long)blockIdx.x * 256 + threadIdx.x;
  const int n = (int)(gid >> 3);
  if (n >= n_nodes) return;
  const int c = (int)(gid & 7) * 8;

  const int beg = offs[n];
  const int cnt = deg[n];

  float a0[8], a1[8], a2[8];
#pragma unroll
  for (int j = 0; j < 8; ++j) { a0[j] = 0.f; a1[j] = 0.f; a2[j] = 0.f; }

  int i = 0;
  for (; i + 3 < cnt; i += 4) {
    const int2 e0 = edgebuf[beg + i];
    const int2 e1 = edgebuf[beg + i + 1];
    const int2 e2 = edgebuf[beg + i + 2];
    const int2 e3 = edgebuf[beg + i + 3];
    const uint4 v0 = *reinterpret_cast<const uint4*>(&xb[(long)(e0.x & SRC_MASK) * 64 + c]);
    const uint4 v1 = *reinterpret_cast<const uint4*>(&xb[(long)(e1.x & SRC_MASK) * 64 + c]);
    const uint4 v2 = *reinterpret_cast<const uint4*>(&xb[(long)(e2.x & SRC_MASK) * 64 + c]);
    const uint4 v3 = *reinterpret_cast<const uint4*>(&xb[(long)(e3.x & SRC_MASK) * 64 + c]);
    const int r0 = (e0.x >> 17) & 3, r1 = (e1.x >> 17) & 3;
    const int r2 = (e2.x >> 17) & 3, r3 = (e3.x >> 17) & 3;
    ACC_EDGE(v0, __int_as_float(e0.y), r0);
    ACC_EDGE(v1, __int_as_float(e1.y), r1);
    ACC_EDGE(v2, __int_as_float(e2.y), r2);
    ACC_EDGE(v3, __int_as_float(e3.y), r3);
  }
  for (; i < cnt; ++i) {
    const int2 ea = edgebuf[beg + i];
    const uint4 va = *reinterpret_cast<const uint4*>(&xb[(long)(ea.x & SRC_MASK) * 64 + c]);
    const int ra = (ea.x >> 17) & 3;
    ACC_EDGE(va, __int_as_float(ea.y), ra);
  }

  uint4 o;
  o.x = f2bf(a0[0]) | (f2bf(a0[1]) << 16);
  o.y = f2bf(a0[2]) | (f2bf(a0[3]) << 16);
  o.z = f2bf(a0[4]) | (f2bf(a0[5]) << 16);
  o.w = f2bf(a0[6]) | (f2bf(a0[7]) << 16);
  *reinterpret_cast<uint4*>(&agg[((long)0 * n_nodes + n) * 64 + c]) = o;
  o.x = f2bf(a1[0]) | (f2bf(a1[1]) << 16);
  o.y = f2bf(a1[2]) | (f2bf(a1[3]) << 16);
  o.z = f2bf(a1[4]) | (f2bf(a1[5]) << 16);
  o.w = f2bf(a1[6]) | (f2bf(a1[7]) << 16);
  *reinterpret_cast<uint4*>(&agg[((long)1 * n_nodes + n) * 64 + c]) = o;
  o.x = f2bf(a2[0]) | (f2bf(a2[1]) << 16);
  o.y = f2bf(a2[2]) | (f2bf(a2[3]) << 16);
  o.z = f2bf(a2[4]) | (f2bf(a2[5]) << 16);
  o.w = f2bf(a2[6]) | (f2bf(a2[7]) << 16);
  *reinterpret_cast<uint4*>(&agg[((long)2 * n_nodes + n) * 64 + c]) = o;
}

// ---------------- mix: x_out = relu(sum_r agg_r @ W_r [+ skip]) via MFMA --------
template <bool SKIP>
__global__ __launch_bounds__(256) void mix_kernel(
    const bf16_t* __restrict__ agg, const float* __restrict__ W,
    const bf16_t* __restrict__ skip, bf16_t* __restrict__ xbout, int n_nodes) {
  __shared__ bf16_t wt[NREL * 64 * 72];  // 27.6 KB
  const int tid = threadIdx.x;

  for (int idx = tid; idx < NREL * 64 * 64; idx += 256) {
    const int r = idx >> 12;
    const int k = (idx >> 6) & 63;
    const int od = idx & 63;
    wt[(r * 64 + od) * 72 + k] = (bf16_t)f2bf(W[idx]);
  }
  __syncthreads();

  const int wid = tid >> 6;
  const int lane = tid & 63;
  const int n0 = blockIdx.x * 64 + wid * 16;
  if (n0 >= n_nodes) return;
  const int node = n0 + (lane & 15);

  short8v bx[NREL][2];
#pragma unroll
  for (int r = 0; r < NREL; ++r) {
    const bf16_t* arow = &agg[((long)r * n_nodes + node) * 64 + (lane >> 4) * 8];
    bx[r][0] = *reinterpret_cast<const short8v*>(arow);
    bx[r][1] = *reinterpret_cast<const short8v*>(arow + 32);
  }

#pragma unroll
  for (int t = 0; t < 4; ++t) {
    float4v acc = {0.f, 0.f, 0.f, 0.f};
#pragma unroll
    for (int r = 0; r < NREL; ++r) {
      const bf16_t* wrow = &wt[(r * 64 + t * 16 + (lane & 15)) * 72 + (lane >> 4) * 8];
      const short8v w0 = *reinterpret_cast<const short8v*>(wrow);
      const short8v w1 = *reinterpret_cast<const short8v*>(wrow + 32);
      acc = __builtin_amdgcn_mfma_f32_16x16x32_bf16(w0, bx[r][0], acc, 0, 0, 0);
      acc = __builtin_amdgcn_mfma_f32_16x16x32_bf16(w1, bx[r][1], acc, 0, 0, 0);
    }
    const int od = t * 16 + (lane >> 4) * 4;
    float vals[4] = {acc[0], acc[1], acc[2], acc[3]};
    if constexpr (SKIP) {
      const uint2 s = *reinterpret_cast<const uint2*>(&skip[(long)node * 64 + od]);
      vals[0] += bf2f(s.x & 0xffff);
      vals[1] += bf2f(s.x >> 16);
      vals[2] += bf2f(s.y & 0xffff);
      vals[3] += bf2f(s.y >> 16);
    }
#pragma unroll
    for (int j = 0; j < 4; ++j) vals[j] = fmaxf(vals[j], 0.f);
    uint2 o;
    o.x = f2bf(vals[0]) | (f2bf(vals[1]) << 16);
    o.y = f2bf(vals[2]) | (f2bf(vals[3]) << 16);
    *reinterpret_cast<uint2*>(&xbout[(long)node * 64 + od]) = o;
  }
}

// ---------------- final mix + heads fused, LDS-slimmed (R20 fix) ----------------
// Per-relation W staging (9.2 KB vs 27.6) with acc[4] carried across r, and
// xs padded to [64][68] (row bank-stride 4 words -> 2-way, free). LDS 52.7KB
// -> ~33KB => 4 blocks/CU; targets R20's 3.1e6 SQ_LDS_BANK_CONFLICT / 23% occ.
__global__ __launch_bounds__(256) void mix_heads_kernel(
    const bf16_t* __restrict__ agg, const float* __restrict__ W,
    const bf16_t* __restrict__ skip, const float* __restrict__ Wa,
    const float* __restrict__ ba, const float* __restrict__ Wb,
    const float* __restrict__ bb, float* __restrict__ out, int n_nodes) {
  __shared__ bf16_t wt[64 * 72];  // 9.2 KB, one relation at a time
  __shared__ float xs[64][68];    // 17.4 KB (272B rows: 16B-aligned, 2-way banks)
  __shared__ float wlt[64][24];   // 6 KB
  __shared__ float bl[23];
  const int tid = threadIdx.x;

  for (int idx = tid; idx < 2 * 64; idx += 256) wlt[idx & 63][idx >> 6] = Wa[idx];
  for (int idx = tid; idx < 21 * 64; idx += 256)
    wlt[idx & 63][2 + (idx >> 6)] = Wb[idx];
  if (tid < 2) bl[tid] = ba[tid];
  else if (tid < 23) bl[tid] = bb[tid - 2];

  const int wid = tid >> 6;
  const int lane = tid & 63;
  const int n0 = blockIdx.x * 64 + wid * 16;
  const bool active = (n0 < n_nodes);
  const int node = n0 + (lane & 15);

  float4v acc[4];
#pragma unroll
  for (int t = 0; t < 4; ++t) acc[t] = (float4v){0.f, 0.f, 0.f, 0.f};

  for (int r = 0; r < NREL; ++r) {
    // stage W_r^T (wt[od][k]) for this relation
    for (int idx = tid; idx < 64 * 64; idx += 256) {
      const int k = idx >> 6;
      const int od = idx & 63;
      wt[od * 72 + k] = (bf16_t)f2bf(W[(r * 64 + k) * 64 + od]);
    }
    __syncthreads();
    if (active) {
      const bf16_t* arow = &agg[((long)r * n_nodes + node) * 64 + (lane >> 4) * 8];
      const short8v b0 = *reinterpret_cast<const short8v*>(arow);
      const short8v b1 = *reinterpret_cast<const short8v*>(arow + 32);
#pragma unroll
      for (int t = 0; t < 4; ++t) {
        const bf16_t* wrow = &wt[(t * 16 + (lane & 15)) * 72 + (lane >> 4) * 8];
        const short8v w0 = *reinterpret_cast<const short8v*>(wrow);
        const short8v w1 = *reinterpret_cast<const short8v*>(wrow + 32);
        acc[t] = __builtin_amdgcn_mfma_f32_16x16x32_bf16(w0, b0, acc[t], 0, 0, 0);
        acc[t] = __builtin_amdgcn_mfma_f32_16x16x32_bf16(w1, b1, acc[t], 0, 0, 0);
      }
    }
    __syncthreads();  // wt reused next r
  }

  if (active) {
#pragma unroll
    for (int t = 0; t < 4; ++t) {
      const int od = t * 16 + (lane >> 4) * 4;
      const uint2 s = *reinterpret_cast<const uint2*>(&skip[(long)node * 64 + od]);
      const int nl = wid * 16 + (lane & 15);
      float4 o;
      o.x = fmaxf(acc[t][0] + bf2f(s.x & 0xffff), 0.f);
      o.y = fmaxf(acc[t][1] + bf2f(s.x >> 16), 0.f);
      o.z = fmaxf(acc[t][2] + bf2f(s.y & 0xffff), 0.f);
      o.w = fmaxf(acc[t][3] + bf2f(s.y >> 16), 0.f);
      *reinterpret_cast<float4*>(&xs[nl][od]) = o;
    }
  }
  __syncthreads();

  const int nbase = blockIdx.x * 64;
  const int nrows = min(64, n_nodes - nbase);
  for (int idx = tid; idx < nrows * 23; idx += 256) {
    const int nn = idx / 23;
    const int sjj = idx % 23;
    float acc2 = 0.f;
#pragma unroll
    for (int k = 0; k < 64; ++k) acc2 += xs[nn][k] * wlt[k][sjj];
    acc2 += bl[sjj];
    const long gnode = nbase + nn;
    if (sjj < 2) out[gnode * 2 + sjj] = acc2;
    else out[(long)n_nodes * 2 + gnode * 21 + (sjj - 2)] = acc2;
  }
}

static inline char* align_up(char* p, size_t a) {
  return (char*)(((uintptr_t)p + a - 1) & ~(uintptr_t)(a - 1));
}

extern "C" void kernel_launch(void* const* d_in, const int* in_sizes, int n_in,
                              void* d_out, int out_size, void* d_ws, size_t ws_size,
                              hipStream_t stream) {
  const float* v    = (const float*)d_in[0];
  const int*   esrc = (const int*)d_in[1];
  const int*   edst = (const int*)d_in[2];
  const int*   erel = (const int*)d_in[3];
  const float* norm = (const float*)d_in[4];
  const float* W1   = (const float*)d_in[5];
  const float* W2   = (const float*)d_in[6];
  const float* W3   = (const float*)d_in[7];
  const float* Wa   = (const float*)d_in[8];
  const float* ba   = (const float*)d_in[9];
  const float* Wb   = (const float*)d_in[10];
  const float* bb   = (const float*)d_in[11];

  const int nN = in_sizes[0] / D;       // 100000
  const int E  = in_sizes[1];           // 1200000
  const int nb = (nN + BSZ - 1) >> BSH; // 196

  // ---- workspace layout
  char* p = (char*)d_ws;
  bf16_t* agg = (bf16_t*)p;           p += 3L * nN * D * sizeof(bf16_t);
  p = align_up(p, 16);
  bf16_t* xbA = (bf16_t*)p;           p += (long)nN * D * sizeof(bf16_t);
  p = align_up(p, 16);
  bf16_t* xbB = (bf16_t*)p;           p += (long)nN * D * sizeof(bf16_t);
  p = align_up(p, 16);
  int* deg      = (int*)p;            p += (long)nN * sizeof(int);
  int* offs     = (int*)p;            p += (long)nN * sizeof(int);
  int* bdeg     = (int*)p;            p += (long)nb * sizeof(int);
  int* boffs    = (int*)p;            p += (long)(nb + 1) * sizeof(int);
  int* bcur     = (int*)p;            p += (long)nb * sizeof(int);
  p = align_up(p, 16);
  int2* edgebuf = (int2*)p;           p += (long)E * sizeof(int2);
  int2* binpay  = (int2*)p;           p += (long)E * sizeof(int2);

  const int tblocks = (nN + 63) / 64;
  const int gblocks = (int)(((long)nN * 8 + 255) / 256);
  const int hblocks = (E + ABLK - 1) / ABLK;
  const int cblocks = (nN * D / 4 + 255) / 256;

  // ---- CSR build
  zero_kernel<<<1, 512, 0, stream>>>(bdeg, bcur, nb);
  bhist_kernel<<<hblocks, ATHR, 0, stream>>>(edst, bdeg, E, nb);
  bscan_kernel<<<1, 512, 0, stream>>>(bdeg, boffs, nb);
  binA_kernel<<<hblocks, ATHR, 0, stream>>>(esrc, edst, erel, norm, boffs, bcur,
                                            binpay, E, nb);
  binB_kernel<<<nb, 512, 0, stream>>>(binpay, boffs, edgebuf, deg, offs, nN);

  // ---- layer 1: xbA = bf16(v); agg = gather(xbA); xbB = relu(agg@W1)
  conv_kernel<<<cblocks, 256, 0, stream>>>(v, xbA, nN * D / 4);
  gather_agg_kernel<<<gblocks, 256, 0, stream>>>(xbA, edgebuf, offs, deg, agg, nN);
  mix_kernel<false><<<tblocks, 256, 0, stream>>>(agg, W1, nullptr, xbB, nN);

  // ---- layer 2: agg = gather(xbB); xbA = relu(agg@W2 + xbB)
  gather_agg_kernel<<<gblocks, 256, 0, stream>>>(xbB, edgebuf, offs, deg, agg, nN);
  mix_kernel<true><<<tblocks, 256, 0, stream>>>(agg, W2, xbB, xbA, nN);

  // ---- layer 3: agg = gather(xbA); out = heads(relu(agg@W3 + xbA))
  gather_agg_kernel<<<gblocks, 256, 0, stream>>>(xbA, edgebuf, offs, deg, agg, nN);
  mix_heads_kernel<<<tblocks, 256, 0, stream>>>(agg, W3, xbA, Wa, ba, Wb, bb,
                                                (float*)d_out, nN);
}

// Round 22
// 235.326 us; speedup vs baseline: 1.0713x; 1.0713x over previous
//
#include <hip/hip_runtime.h>

#define D 64
#define NREL 3
#define SRC_MASK 0x1FFFF      // 17 bits: N=100000 < 2^17
#define ATHR 512
#define APT 8
#define ABLK (ATHR * APT)     // 4096 edges per block (bhist, binA)
#define BSH 9                 // 512-node buckets
#define BSZ 512

typedef unsigned short bf16_t;
typedef __attribute__((ext_vector_type(8))) short short8v;   // 8 bf16 = 4 VGPRs
typedef __attribute__((ext_vector_type(4))) float float4v;

__device__ __forceinline__ float bf2f(unsigned int u16) {
  return __uint_as_float(u16 << 16);
}
__device__ __forceinline__ unsigned int f2bf(float f) {
  unsigned int x = __float_as_uint(f);
  return (x + 0x7fffu + ((x >> 16) & 1u)) >> 16;  // round-to-nearest-even
}

// ---------------- tiny zero (R12-verified: replaces 2x ~40us fill dispatches) ----
__global__ __launch_bounds__(512) void zero_kernel(int* __restrict__ a,
                                                   int* __restrict__ b, int n) {
  const int t = threadIdx.x;
  for (int i = t; i < n; i += 512) { a[i] = 0; b[i] = 0; }
}

// ---------------- transform via MFMA (R11-verified: 4x faster than VALU) ----------
// F32IN: read f32 input and convert in-register (folds the old conv_kernel).
template <bool F32IN>
__global__ __launch_bounds__(256) void transform_kernel(
    const void* __restrict__ xin, const float* __restrict__ W,
    bf16_t* __restrict__ hr, int n_nodes) {
  __shared__ bf16_t wt[NREL * 64 * 72];  // 27.6 KB
  const int tid = threadIdx.x;

  for (int idx = tid; idx < NREL * 64 * 64; idx += 256) {
    const int r = idx >> 12;
    const int k = (idx >> 6) & 63;
    const int od = idx & 63;
    wt[(r * 64 + od) * 72 + k] = (bf16_t)f2bf(W[idx]);
  }
  __syncthreads();

  const int wid = tid >> 6;
  const int lane = tid & 63;
  const int n0 = blockIdx.x * 64 + wid * 16;
  if (n0 >= n_nodes) return;

  short8v bx0, bx1;
  if constexpr (F32IN) {
    const float* xrow =
        (const float*)xin + (long)(n0 + (lane & 15)) * 64 + (lane >> 4) * 8;
    const float4 f0 = *reinterpret_cast<const float4*>(xrow);
    const float4 f1 = *reinterpret_cast<const float4*>(xrow + 4);
    const float4 f2 = *reinterpret_cast<const float4*>(xrow + 32);
    const float4 f3 = *reinterpret_cast<const float4*>(xrow + 36);
    bx0[0] = (short)f2bf(f0.x); bx0[1] = (short)f2bf(f0.y);
    bx0[2] = (short)f2bf(f0.z); bx0[3] = (short)f2bf(f0.w);
    bx0[4] = (short)f2bf(f1.x); bx0[5] = (short)f2bf(f1.y);
    bx0[6] = (short)f2bf(f1.z); bx0[7] = (short)f2bf(f1.w);
    bx1[0] = (short)f2bf(f2.x); bx1[1] = (short)f2bf(f2.y);
    bx1[2] = (short)f2bf(f2.z); bx1[3] = (short)f2bf(f2.w);
    bx1[4] = (short)f2bf(f3.x); bx1[5] = (short)f2bf(f3.y);
    bx1[6] = (short)f2bf(f3.z); bx1[7] = (short)f2bf(f3.w);
  } else {
    const bf16_t* xrow =
        (const bf16_t*)xin + (long)(n0 + (lane & 15)) * 64 + (lane >> 4) * 8;
    bx0 = *reinterpret_cast<const short8v*>(xrow);
    bx1 = *reinterpret_cast<const short8v*>(xrow + 32);
  }

  const int node = n0 + (lane & 15);
#pragma unroll
  for (int r = 0; r < NREL; ++r) {
#pragma unroll
    for (int t = 0; t < 4; ++t) {
      const bf16_t* wrow =
          &wt[(r * 64 + t * 16 + (lane & 15)) * 72 + (lane >> 4) * 8];
      const short8v a0 = *reinterpret_cast<const short8v*>(wrow);
      const short8v a1 = *reinterpret_cast<const short8v*>(wrow + 32);
      float4v acc = {0.f, 0.f, 0.f, 0.f};
      acc = __builtin_amdgcn_mfma_f32_16x16x32_bf16(a0, bx0, acc, 0, 0, 0);
      acc = __builtin_amdgcn_mfma_f32_16x16x32_bf16(a1, bx1, acc, 0, 0, 0);
      const int od = t * 16 + (lane >> 4) * 4;
      uint2 o;
      o.x = f2bf(acc[0]) | (f2bf(acc[1]) << 16);
      o.y = f2bf(acc[2]) | (f2bf(acc[3]) << 16);
      *reinterpret_cast<uint2*>(&hr[((long)r * n_nodes + node) * 64 + od]) = o;
    }
  }
}

// ---------------- CSR build (bucket-level only; no node-level atomics) ----------
__global__ __launch_bounds__(ATHR) void bhist_kernel(
    const int* __restrict__ dst, int* __restrict__ bdeg, int n_edges, int nb) {
  __shared__ int cnt[200];
  const int t = threadIdx.x;
  for (int b = t; b < nb; b += ATHR) cnt[b] = 0;
  __syncthreads();
  const long e0 = (long)blockIdx.x * ABLK;
#pragma unroll
  for (int i = 0; i < APT; ++i) {
    const long e = e0 + t + (long)i * ATHR;
    if (e < n_edges) atomicAdd(&cnt[dst[e] >> BSH], 1);
  }
  __syncthreads();
  for (int b = t; b < nb; b += ATHR)
    if (cnt[b]) atomicAdd(&bdeg[b], cnt[b]);
}

// Single block: exclusive scan of bdeg[nb] -> boffs[nb+1] (nb <= 512).
__global__ __launch_bounds__(512) void bscan_kernel(
    const int* __restrict__ bdeg, int* __restrict__ boffs, int nb) {
  __shared__ int s[512];
  const int t = threadIdx.x;
  const int v = (t < nb) ? bdeg[t] : 0;
  s[t] = v;
  __syncthreads();
  for (int off = 1; off < 512; off <<= 1) {
    const int add = (t >= off) ? s[t - off] : 0;
    __syncthreads();
    s[t] += add;
    __syncthreads();
  }
  if (t < nb) boffs[t] = s[t] - v;
  if (t == 511) boffs[nb] = s[nb - 1];
}

// Phase A v2 (R19-verified): count -> LDS scan -> stage payloads bucket-ordered
// in LDS -> reserve global ranges -> linear flush (coalesced segments).
__global__ __launch_bounds__(ATHR) void binA_kernel(
    const int* __restrict__ src, const int* __restrict__ dst,
    const int* __restrict__ rel, const float* __restrict__ norm,
    const int* __restrict__ boffs, int* __restrict__ bcur,
    int2* __restrict__ binpay, int n_edges, int nb) {
  __shared__ int cnt[256];
  __shared__ int incl[256];
  __shared__ int gbase[200];
  __shared__ int2 staged[ABLK];           // 32 KB
  __shared__ unsigned char sbk[ABLK];     // 4 KB
  const int t = threadIdx.x;
  const long e0 = (long)blockIdx.x * ABLK;

  for (int b = t; b < 256; b += ATHR) cnt[b] = 0;
  __syncthreads();

  // pass 1: load edges, count per bucket, remember slot
  int2 pay[APT];
  int bk[APT], slot[APT];
#pragma unroll
  for (int i = 0; i < APT; ++i) {
    const long e = e0 + t + (long)i * ATHR;
    if (e < n_edges) {
      const int d = dst[e];
      bk[i] = d >> BSH;
      pay[i] = make_int2(src[e] | (rel[e] << 17) | ((d & (BSZ - 1)) << 19),
                         __float_as_int(norm[e]));
      slot[i] = atomicAdd(&cnt[bk[i]], 1);
    } else {
      bk[i] = -1;
    }
  }
  __syncthreads();

  // inclusive Hillis-Steele scan over 256 bucket counters
  if (t < 256) incl[t] = cnt[t];
  __syncthreads();
  for (int off = 1; off < 256; off <<= 1) {
    int add = 0;
    if (t < 256 && t >= off) add = incl[t - off];
    __syncthreads();
    if (t < 256) incl[t] += add;
    __syncthreads();
  }

  // reserve contiguous global range per bucket
  for (int b = t; b < nb; b += ATHR) {
    const int c = cnt[b];
    gbase[b] = c ? (boffs[b] + atomicAdd(&bcur[b], c)) : 0;
  }
  __syncthreads();

  // pass 2: place into LDS staging, ordered by bucket
#pragma unroll
  for (int i = 0; i < APT; ++i) {
    if (bk[i] >= 0) {
      const int pos = incl[bk[i]] - cnt[bk[i]] + slot[i];
      staged[pos] = pay[i];
      sbk[pos] = (unsigned char)bk[i];
    }
  }
  __syncthreads();

  // pass 3: linear flush -> coalesced global writes
  const int nv = (int)min((long)ABLK, (long)(n_edges - e0));
  for (int j = t; j < nv; j += ATHR) {
    const int b = sbk[j];
    const int excl = incl[b] - cnt[b];
    binpay[gbase[b] + j - excl] = staged[j];
  }
}

// Phase B: one 512-thread block per 512-node bucket (R16-verified).
__global__ __launch_bounds__(512) void binB_kernel(
    const int2* __restrict__ binpay, const int* __restrict__ boffs,
    int2* __restrict__ edgebuf, int* __restrict__ deg, int* __restrict__ offs,
    int n_nodes) {
  __shared__ int cnt[512];
  __shared__ int ss[512];
  __shared__ int cur[512];
  const int b = blockIdx.x;
  const int t = threadIdx.x;
  cnt[t] = 0;
  __syncthreads();
  const int start = boffs[b];
  const int end = boffs[b + 1];
  for (int i = start + t; i < end; i += 512)
    atomicAdd(&cnt[((unsigned)binpay[i].x >> 19) & (BSZ - 1)], 1);
  __syncthreads();
  const int v = cnt[t];
  ss[t] = v;
  __syncthreads();
  for (int off = 1; off < 512; off <<= 1) {
    const int add = (t >= off) ? ss[t - off] : 0;
    __syncthreads();
    ss[t] += add;
    __syncthreads();
  }
  const int excl = ss[t] - v;
  cur[t] = excl;
  const int node = (b << BSH) + t;
  if (node < n_nodes) {
    deg[node] = v;
    offs[node] = start + excl;
  }
  __syncthreads();
  for (int i = start + t; i < end; i += 512) {
    const int2 pay = binpay[i];
    const int dl = ((unsigned)pay.x >> 19) & (BSZ - 1);
    const int pos = start + atomicAdd(&cur[dl], 1);
    edgebuf[pos] = pay;
  }
}

// ---------------- gather core (8 threads/node, uint4 hr reads) ----------------
__device__ __forceinline__ void gather_core(
    const bf16_t* __restrict__ hr, const int2* __restrict__ edgebuf,
    int beg, int cnt, int n_nodes, int c, float* a /*[8]*/) {
  float acc0[8], acc1[8];
#pragma unroll
  for (int j = 0; j < 8; ++j) { acc0[j] = 0.f; acc1[j] = 0.f; }

  int i = 0;
  for (; i + 3 < cnt; i += 4) {
    const int2 e0 = edgebuf[beg + i];
    const int2 e1 = edgebuf[beg + i + 1];
    const int2 e2 = edgebuf[beg + i + 2];
    const int2 e3 = edgebuf[beg + i + 3];
    const uint4 v0 = *reinterpret_cast<const uint4*>(
        &hr[((long)((((unsigned)e0.x) >> 17) & 3) * n_nodes + (e0.x & SRC_MASK)) * 64 + c]);
    const uint4 v1 = *reinterpret_cast<const uint4*>(
        &hr[((long)((((unsigned)e1.x) >> 17) & 3) * n_nodes + (e1.x & SRC_MASK)) * 64 + c]);
    const uint4 v2 = *reinterpret_cast<const uint4*>(
        &hr[((long)((((unsigned)e2.x) >> 17) & 3) * n_nodes + (e2.x & SRC_MASK)) * 64 + c]);
    const uint4 v3 = *reinterpret_cast<const uint4*>(
        &hr[((long)((((unsigned)e3.x) >> 17) & 3) * n_nodes + (e3.x & SRC_MASK)) * 64 + c]);
    const float n0 = __int_as_float(e0.y), n1 = __int_as_float(e1.y);
    const float n2 = __int_as_float(e2.y), n3 = __int_as_float(e3.y);
    const unsigned int w0[4] = {v0.x, v0.y, v0.z, v0.w};
    const unsigned int w1[4] = {v1.x, v1.y, v1.z, v1.w};
    const unsigned int w2[4] = {v2.x, v2.y, v2.z, v2.w};
    const unsigned int w3[4] = {v3.x, v3.y, v3.z, v3.w};
#pragma unroll
    for (int j = 0; j < 4; ++j) {
      acc0[2 * j + 0] += bf2f(w0[j] & 0xffff) * n0;
      acc0[2 * j + 1] += bf2f(w0[j] >> 16) * n0;
      acc1[2 * j + 0] += bf2f(w1[j] & 0xffff) * n1;
      acc1[2 * j + 1] += bf2f(w1[j] >> 16) * n1;
      acc0[2 * j + 0] += bf2f(w2[j] & 0xffff) * n2;
      acc0[2 * j + 1] += bf2f(w2[j] >> 16) * n2;
      acc1[2 * j + 0] += bf2f(w3[j] & 0xffff) * n3;
      acc1[2 * j + 1] += bf2f(w3[j] >> 16) * n3;
    }
  }
  for (; i < cnt; ++i) {
    const int2 ea = edgebuf[beg + i];
    const float na = __int_as_float(ea.y);
    const uint4 va = *reinterpret_cast<const uint4*>(
        &hr[((long)((((unsigned)ea.x) >> 17) & 3) * n_nodes + (ea.x & SRC_MASK)) * 64 + c]);
    const unsigned int wa[4] = {va.x, va.y, va.z, va.w};
#pragma unroll
    for (int j = 0; j < 4; ++j) {
      acc0[2 * j + 0] += bf2f(wa[j] & 0xffff) * na;
      acc0[2 * j + 1] += bf2f(wa[j] >> 16) * na;
    }
  }
#pragma unroll
  for (int j = 0; j < 8; ++j) a[j] = acc0[j] + acc1[j];
}

// ---------------- fused gather + skip + relu (layers 1-2) ----------------
__global__ __launch_bounds__(256) void gather_kernel(
    const bf16_t* __restrict__ hr, const int2* __restrict__ edgebuf,
    const int* __restrict__ offs, const int* __restrict__ deg,
    const float* __restrict__ skip, float* __restrict__ out,
    bf16_t* __restrict__ xbout, int n_nodes) {
  const long gid = (long)blockIdx.x * 256 + threadIdx.x;
  const int n = (int)(gid >> 3);
  if (n >= n_nodes) return;
  const int c = (int)(gid & 7) * 8;

  float a[8];
  gather_core(hr, edgebuf, offs[n], deg[n], n_nodes, c, a);
  if (skip != nullptr) {
    const float4 s0 = *reinterpret_cast<const float4*>(&skip[(long)n * 64 + c]);
    const float4 s1 = *reinterpret_cast<const float4*>(&skip[(long)n * 64 + c + 4]);
    a[0] += s0.x; a[1] += s0.y; a[2] += s0.z; a[3] += s0.w;
    a[4] += s1.x; a[5] += s1.y; a[6] += s1.z; a[7] += s1.w;
  }
#pragma unroll
  for (int j = 0; j < 8; ++j) a[j] = fmaxf(a[j], 0.f);
  float4 o0 = {a[0], a[1], a[2], a[3]};
  float4 o1 = {a[4], a[5], a[6], a[7]};
  *reinterpret_cast<float4*>(&out[(long)n * 64 + c]) = o0;
  *reinterpret_cast<float4*>(&out[(long)n * 64 + c + 4]) = o1;
  uint4 ob;
  ob.x = f2bf(a[0]) | (f2bf(a[1]) << 16);
  ob.y = f2bf(a[2]) | (f2bf(a[3]) << 16);
  ob.z = f2bf(a[4]) | (f2bf(a[5]) << 16);
  ob.w = f2bf(a[6]) | (f2bf(a[7]) << 16);
  *reinterpret_cast<uint4*>(&xbout[(long)n * 64 + c]) = ob;
}

// ---------------- layer-3: gather + skip + relu + BOTH HEADS (R17-verified) -----
// LDS x-tile + transposed wlt[k][s] (conflict-free). R18's LDS-free shuffle
// variant measured WORSE (49 vs 45us) -> this is the better measured point.
__global__ __launch_bounds__(256) void gather_heads_kernel(
    const bf16_t* __restrict__ hr, const int2* __restrict__ edgebuf,
    const int* __restrict__ offs, const int* __restrict__ deg,
    const float* __restrict__ skip, const float* __restrict__ Wa,
    const float* __restrict__ ba, const float* __restrict__ Wb,
    const float* __restrict__ bb, float* __restrict__ out, int n_nodes) {
  __shared__ float xs[32][72];   // 9.2 KB, float4-aligned rows
  __shared__ float wlt[64][24];  // [k][s]
  __shared__ float bl[23];
  const int tid = threadIdx.x;

  for (int idx = tid; idx < 2 * 64; idx += 256) wlt[idx & 63][idx >> 6] = Wa[idx];
  for (int idx = tid; idx < 21 * 64; idx += 256)
    wlt[idx & 63][2 + (idx >> 6)] = Wb[idx];
  if (tid < 2) bl[tid] = ba[tid];
  else if (tid < 23) bl[tid] = bb[tid - 2];

  const int nbase = blockIdx.x * 32;
  const int nl = tid >> 3;
  const int n = nbase + nl;
  const int c = (tid & 7) * 8;

  if (n < n_nodes) {
    float a[8];
    gather_core(hr, edgebuf, offs[n], deg[n], n_nodes, c, a);
    if (skip != nullptr) {
      const float4 s0 = *reinterpret_cast<const float4*>(&skip[(long)n * 64 + c]);
      const float4 s1 = *reinterpret_cast<const float4*>(&skip[(long)n * 64 + c + 4]);
      a[0] += s0.x; a[1] += s0.y; a[2] += s0.z; a[3] += s0.w;
      a[4] += s1.x; a[5] += s1.y; a[6] += s1.z; a[7] += s1.w;
    }
#pragma unroll
    for (int j = 0; j < 8; ++j) a[j] = fmaxf(a[j], 0.f);
    float4 o0 = {a[0], a[1], a[2], a[3]};
    float4 o1 = {a[4], a[5], a[6], a[7]};
    *reinterpret_cast<float4*>(&xs[nl][c]) = o0;
    *reinterpret_cast<float4*>(&xs[nl][c + 4]) = o1;
  }
  __syncthreads();

  const int nrows = min(32, n_nodes - nbase);
  for (int idx = tid; idx < nrows * 23; idx += 256) {
    const int nn = idx / 23;
    const int s = idx % 23;
    float acc = 0.f;
#pragma unroll
    for (int k = 0; k < 64; ++k) acc += xs[nn][k] * wlt[k][s];
    acc += bl[s];
    const long node = nbase + nn;
    if (s < 2) out[node * 2 + s] = acc;
    else out[(long)n_nodes * 2 + node * 21 + (s - 2)] = acc;
  }
}

static inline char* align_up(char* p, size_t a) {
  return (char*)(((uintptr_t)p + a - 1) & ~(uintptr_t)(a - 1));
}

extern "C" void kernel_launch(void* const* d_in, const int* in_sizes, int n_in,
                              void* d_out, int out_size, void* d_ws, size_t ws_size,
                              hipStream_t stream) {
  const float* v    = (const float*)d_in[0];
  const int*   esrc = (const int*)d_in[1];
  const int*   edst = (const int*)d_in[2];
  const int*   erel = (const int*)d_in[3];
  const float* norm = (const float*)d_in[4];
  const float* W1   = (const float*)d_in[5];
  const float* W2   = (const float*)d_in[6];
  const float* W3   = (const float*)d_in[7];
  const float* Wa   = (const float*)d_in[8];
  const float* ba   = (const float*)d_in[9];
  const float* Wb   = (const float*)d_in[10];
  const float* bb   = (const float*)d_in[11];

  const int nN = in_sizes[0] / D;       // 100000
  const int E  = in_sizes[1];           // 1200000
  const int nb = (nN + BSZ - 1) >> BSH; // 512-node buckets -> 196

  // ---- workspace layout
  char* p = (char*)d_ws;
  bf16_t* hr = (bf16_t*)p;            p += 3L * nN * D * sizeof(bf16_t);
  p = align_up(p, 16);
  bf16_t* xb = (bf16_t*)p;            p += (long)nN * D * sizeof(bf16_t);
  p = align_up(p, 16);
  float* bufA = (float*)p;            p += (long)nN * D * sizeof(float);
  float* bufB = (float*)p;            p += (long)nN * D * sizeof(float);
  int* deg      = (int*)p;            p += (long)nN * sizeof(int);
  int* offs     = (int*)p;            p += (long)nN * sizeof(int);
  int* bdeg     = (int*)p;            p += (long)nb * sizeof(int);
  int* boffs    = (int*)p;            p += (long)(nb + 1) * sizeof(int);
  int* bcur     = (int*)p;            p += (long)nb * sizeof(int);
  p = align_up(p, 16);
  int2* edgebuf = (int2*)p;           p += (long)E * sizeof(int2);
  int2* binpay  = (int2*)p;           p += (long)E * sizeof(int2);

  const int tblocks = (nN + 63) / 64;
  const int gblocks = (int)(((long)nN * 8 + 255) / 256);
  const int ghblocks = (nN + 31) / 32;
  const int hblocks = (E + ABLK - 1) / ABLK;

  // ---- CSR build (bucket-level histogram only; once per call)
  zero_kernel<<<1, 512, 0, stream>>>(bdeg, bcur, nb);
  bhist_kernel<<<hblocks, ATHR, 0, stream>>>(edst, bdeg, E, nb);
  bscan_kernel<<<1, 512, 0, stream>>>(bdeg, boffs, nb);
  binA_kernel<<<hblocks, ATHR, 0, stream>>>(esrc, edst, erel, norm, boffs, bcur,
                                            binpay, E, nb);
  binB_kernel<<<nb, 512, 0, stream>>>(binpay, boffs, edgebuf, deg, offs, nN);

  // ---- layer 1: v (f32, converted in-kernel) -> hr; gather -> bufA + xb
  transform_kernel<true><<<tblocks, 256, 0, stream>>>(v, W1, hr, nN);
  gather_kernel<<<gblocks, 256, 0, stream>>>(hr, edgebuf, offs, deg, nullptr,
                                             bufA, xb, nN);

  // ---- layer 2: xb -> hr; gather(skip=bufA) -> bufB + xb
  transform_kernel<false><<<tblocks, 256, 0, stream>>>(xb, W2, hr, nN);
  gather_kernel<<<gblocks, 256, 0, stream>>>(hr, edgebuf, offs, deg, bufA,
                                             bufB, xb, nN);

  // ---- layer 3: xb -> hr; gather(skip=bufB) + heads -> d_out (R17 fused)
  transform_kernel<false><<<tblocks, 256, 0, stream>>>(xb, W3, hr, nN);
  gather_heads_kernel<<<ghblocks, 256, 0, stream>>>(hr, edgebuf, offs, deg, bufB,
                                                    Wa, ba, Wb, bb,
                                                    (float*)d_out, nN);
}